// Round 10
// baseline (2159.983 us; speedup 1.0000x reference)
//
#include <hip/hip_runtime.h>
#include <cstdint>

#define BB   4096
#define TT   7
#define INF  512
#define HH   1024
#define OUTF 512
#define G3   3072   // 3*H

typedef short bf16x8 __attribute__((ext_vector_type(8)));
typedef float f32x4  __attribute__((ext_vector_type(4)));

static __device__ __forceinline__ unsigned short f2bf(float f) {
  unsigned u = __float_as_uint(f);
  unsigned r = ((u >> 16) & 1u) + 0x7FFFu;   // RNE
  return (unsigned short)((u + r) >> 16);
}
static __device__ __forceinline__ float bf2f(unsigned short s) {
  return __uint_as_float(((unsigned)s) << 16);
}

#define GLDS16(gp, lp)                                                        \
  __builtin_amdgcn_global_load_lds(                                           \
      (const __attribute__((address_space(1))) void*)(gp),                    \
      (__attribute__((address_space(3))) void*)(lp), 16, 0, 0)

__device__ __forceinline__ int xcd_swz(int bid, int nwg) {
  return (bid & 7) * (nwg >> 3) + (bid >> 3);   // bijective: nwg % 8 == 0
}

__global__ __launch_bounds__(256)
void cvt_f32_to_bf16_x4(const float* __restrict__ in, unsigned short* __restrict__ out, int n4) {
  int i = blockIdx.x * 256 + threadIdx.x;
  if (i >= n4) return;
  const float4 v = ((const float4*)in)[i];
  ushort4 o;
  o.x = f2bf(v.x); o.y = f2bf(v.y); o.z = f2bf(v.z); o.w = f2bf(v.w);
  ((ushort4*)out)[i] = o;
}

// ---------------------------------------------------------------------------
// Generic GEMM core (r5/r9-proven): C = A @ W^T + bias. 128x128, BK=64,
// single-buffered 32 KB LDS, chunk-XOR swizzle (0 conflicts measured).
// mode: 0 f32; 1 f32 tanh; 2 f32 tanh+add; 3 bf16.
// ---------------------------------------------------------------------------
__device__ __forceinline__ void gemm_core128(
    const unsigned short* __restrict__ A, long lda, long bm,
    const unsigned short* __restrict__ Wp, long ldw, int K,
    const float* __restrict__ biasp,
    void* __restrict__ Cp, long ldc,
    const float* __restrict__ addp, long ldadd, int mode)
{
  __shared__ __attribute__((aligned(16))) unsigned short sm[256 * 64];  // 32 KB
  unsigned short* As = sm;
  unsigned short* Ws = sm + 128 * 64;
  __attribute__((address_space(3))) unsigned short* lAs =
      (__attribute__((address_space(3))) unsigned short*)As;
  __attribute__((address_space(3))) unsigned short* lWs =
      (__attribute__((address_space(3))) unsigned short*)Ws;

  const int tid  = threadIdx.x;
  const int lane = tid & 63;
  const int wid  = tid >> 6;
  const int wr = (wid >> 1) * 64;
  const int wc = (wid & 1) * 64;
  const int fr = lane & 15;
  const int q2 = lane >> 4;

  const unsigned short* gpa[4];
  const unsigned short* gpw[4];
  int lof[4];
#pragma unroll
  for (int r = 0; r < 4; ++r) {
    const int id = r * 256 + tid;
    const int row = id >> 3, cc = id & 7;
    gpa[r] = A + (bm + row) * lda + (cc ^ (row & 7)) * 8;
    gpw[r] = Wp + (long)row * ldw + (cc ^ (row & 7)) * 8;
    lof[r] = id * 8;
  }

  f32x4 acc[4][4] = {};
  for (int kt = 0; kt < K; kt += 64) {
    if (kt) __syncthreads();
#pragma unroll
    for (int r = 0; r < 4; ++r) GLDS16(gpa[r] + kt, lAs + lof[r]);
#pragma unroll
    for (int r = 0; r < 4; ++r) GLDS16(gpw[r] + kt, lWs + lof[r]);
    __syncthreads();

#pragma unroll
    for (int ks = 0; ks < 2; ++ks) {
      bf16x8 af[4], wf[4];
#pragma unroll
      for (int i = 0; i < 4; ++i) {
        const int row = wr + i * 16 + fr;
        const int ch  = (ks * 4 + q2) ^ (row & 7);
        af[i] = *(const bf16x8*)&As[row * 64 + ch * 8];
      }
#pragma unroll
      for (int i = 0; i < 4; ++i) {
        const int row = wc + i * 16 + fr;
        const int ch  = (ks * 4 + q2) ^ (row & 7);
        wf[i] = *(const bf16x8*)&Ws[row * 64 + ch * 8];
      }
#pragma unroll
      for (int mi = 0; mi < 4; ++mi)
#pragma unroll
        for (int ni = 0; ni < 4; ++ni)
          acc[mi][ni] = __builtin_amdgcn_mfma_f32_16x16x32_bf16(af[mi], wf[ni], acc[mi][ni], 0, 0, 0);
    }
  }

  const int q = lane >> 4;
#pragma unroll
  for (int ni = 0; ni < 4; ++ni) {
    const int col = wc + ni * 16 + fr;
    const float bv = biasp[col];
#pragma unroll
    for (int mi = 0; mi < 4; ++mi) {
      const long row = bm + wr + mi * 16 + q * 4;
#pragma unroll
      for (int j = 0; j < 4; ++j) {
        const float v = acc[mi][ni][j] + bv;
        if (mode == 0)      ((float*)Cp)[(row + j) * ldc + col] = v;
        else if (mode == 1) ((float*)Cp)[(row + j) * ldc + col] = tanhf(v);
        else if (mode == 2) ((float*)Cp)[(row + j) * ldc + col] = tanhf(v) + addp[(row + j) * ldadd + col];
        else                ((unsigned short*)Cp)[(row + j) * ldc + col] = f2bf(v);
      }
    }
  }
}

// ---------------------------------------------------------------------------
// FUSED gh-GEMM + GRU gate. Block: rows [bm,bm+128) x hidden cols [cn,cn+64),
// computing gh for W-rows {c, c+1024, c+2048} (the r/z/n sections) in one
// tile: B-staging = 192 W-rows (3 sections x 64). Wave tile 64 x (3x32),
// panel-major frags -> lane holds (r,z,n) of the SAME c in acc[mi][k],
// acc[mi][2+k], acc[mi][4+k]: gate computes entirely in-lane. gh stays f32
// (never hits memory). h is ping-pong buffered (hold -> hnew) because other
// blocks still read hold while this block's epilogue writes.
// ---------------------------------------------------------------------------
template<bool AUX>
__global__ __launch_bounds__(256)
void k_ghg(const unsigned short* __restrict__ hold,
           const unsigned short* __restrict__ Whh,   // [3072][1024]
           const float* __restrict__ bhh,            // [3072]
           const unsigned short* __restrict__ gi,    // [4096][3072] bf16 (incl. bih)
           unsigned short* __restrict__ hnew,        // [4096][1024] bf16
           float* __restrict__ auxp)                 // per-block partial (AUX)
{
  __shared__ __attribute__((aligned(16))) unsigned short sm[(128 + 192) * 64]; // 40 KB
  unsigned short* As = sm;              // [128][64]
  unsigned short* Ws = sm + 128 * 64;   // [192][64] (3 sections x 64 rows)
  __attribute__((address_space(3))) unsigned short* lAs =
      (__attribute__((address_space(3))) unsigned short*)As;
  __attribute__((address_space(3))) unsigned short* lWs =
      (__attribute__((address_space(3))) unsigned short*)Ws;

  const int wg = xcd_swz(blockIdx.x, gridDim.x);    // 512 blocks
  const long bm = (long)(wg & 31) * 128;            // row tile
  const int  cn = (wg >> 5) * 64;                   // hidden-col tile (0..960)

  const int tid  = threadIdx.x;
  const int lane = tid & 63;
  const int wid  = tid >> 6;
  const int wr  = (wid >> 1) * 64;     // 0 / 64
  const int wcs = (wid & 1) * 32;      // 0 / 32 (within the 64 hidden cols)
  const int fr = lane & 15;
  const int q2 = lane >> 4;

  // staging pointers. A: 128 rows x 8 chunks = 1024 -> 4 rounds.
  // W: 192 rows x 8 chunks = 1536 -> 6 rounds; LDS row s*64+rr maps to
  // global W row s*1024 + cn + rr.
  const unsigned short* gpa[4];
  const unsigned short* gpw[6];
  int lofa[4], lofw[6];
#pragma unroll
  for (int r = 0; r < 4; ++r) {
    const int id = r * 256 + tid;
    const int row = id >> 3, cc = id & 7;
    gpa[r] = hold + (bm + row) * HH + (cc ^ (row & 7)) * 8;
    lofa[r] = id * 8;
  }
#pragma unroll
  for (int r = 0; r < 6; ++r) {
    const int id = r * 256 + tid;
    const int row = id >> 3, cc = id & 7;      // row in [0,192)
    const int s = row >> 6, rr = row & 63;
    gpw[r] = Whh + ((long)(s * 1024 + cn + rr)) * HH + (cc ^ (row & 7)) * 8;
    lofw[r] = id * 8;
  }

  f32x4 acc[4][6] = {};
  for (int kt = 0; kt < HH; kt += 64) {
    if (kt) __syncthreads();
#pragma unroll
    for (int r = 0; r < 4; ++r) GLDS16(gpa[r] + kt, lAs + lofa[r]);
#pragma unroll
    for (int r = 0; r < 6; ++r) GLDS16(gpw[r] + kt, lWs + lofw[r]);
    __syncthreads();

#pragma unroll
    for (int ks = 0; ks < 2; ++ks) {
      bf16x8 af[4], wf[6];
#pragma unroll
      for (int i = 0; i < 4; ++i) {
        const int row = wr + i * 16 + fr;
        const int ch  = (ks * 4 + q2) ^ (row & 7);
        af[i] = *(const bf16x8*)&As[row * 64 + ch * 8];
      }
#pragma unroll
      for (int p = 0; p < 3; ++p)
#pragma unroll
        for (int k2 = 0; k2 < 2; ++k2) {
          const int row = p * 64 + wcs + k2 * 16 + fr;
          const int ch  = (ks * 4 + q2) ^ (row & 7);
          wf[p * 2 + k2] = *(const bf16x8*)&Ws[row * 64 + ch * 8];
        }
#pragma unroll
      for (int mi = 0; mi < 4; ++mi)
#pragma unroll
        for (int ni = 0; ni < 6; ++ni)
          acc[mi][ni] = __builtin_amdgcn_mfma_f32_16x16x32_bf16(af[mi], wf[ni], acc[mi][ni], 0, 0, 0);
    }
  }

  // ---- fused gate epilogue: h = (1-z)*n + z*h_old, all in-lane ----
  const int q = lane >> 4;
  float vsum = 0.f;
#pragma unroll
  for (int k2 = 0; k2 < 2; ++k2) {
    const int c = cn + wcs + k2 * 16 + fr;      // hidden index
    const float br = bhh[c], bz = bhh[1024 + c], bn = bhh[2048 + c];
#pragma unroll
    for (int mi = 0; mi < 4; ++mi) {
      const long row = bm + wr + mi * 16 + q * 4;
#pragma unroll
      for (int j = 0; j < 4; ++j) {
        const long rj = row + j;
        const float ghr = acc[mi][k2][j]     + br;
        const float ghz = acc[mi][2 + k2][j] + bz;
        const float ghn = acc[mi][4 + k2][j] + bn;
        const unsigned short* gp = gi + rj * G3 + c;
        const float gir = bf2f(gp[0]);
        const float giz = bf2f(gp[HH]);
        const float gin = bf2f(gp[2 * HH]);
        const float r = 1.f / (1.f + __expf(-(gir + ghr)));
        const float z = 1.f / (1.f + __expf(-(giz + ghz)));
        const float n = tanhf(gin + r * ghn);
        const float ho = bf2f(hold[rj * HH + c]);
        const float h = (1.f - z) * n + z * ho;
        hnew[rj * HH + c] = f2bf(h);
        if (AUX) vsum += h * h;
      }
    }
  }
  if (AUX) {
#pragma unroll
    for (int off = 32; off > 0; off >>= 1) vsum += __shfl_down(vsum, off);
    __shared__ float wsum[4];
    if (lane == 0) wsum[wid] = vsum;
    __syncthreads();
    if (tid == 0) auxp[blockIdx.x] = wsum[0] + wsum[1] + wsum[2] + wsum[3];
  }
}

// k_pre: gi1(t) [768 blocks] and (t>0) out(t-1)=tanh(h2@Wo2+bo2)+o1t [128].
__global__ __launch_bounds__(256)
void k_pre(const unsigned short* __restrict__ xb_t,
           const unsigned short* __restrict__ wih1b, const float* __restrict__ bih1,
           unsigned short* __restrict__ gi1b,
           const unsigned short* __restrict__ h2o,
           const unsigned short* __restrict__ wo2b, const float* __restrict__ bo2,
           const float* __restrict__ o1t_prev, float* __restrict__ out_prev)
{
  const int wg = xcd_swz(blockIdx.x, gridDim.x);   // 768 or 896
  if (wg < 768) {
    const int bx = wg & 31, by = wg >> 5;          // by 0..23
    gemm_core128(xb_t, (long)TT * INF, (long)bx * 128, wih1b + (long)by * 128 * INF,
                 INF, INF, bih1 + by * 128, gi1b + by * 128, G3, nullptr, 0, 3);
  } else {
    const int idx = wg - 768;
    const int bx = idx & 31, by = idx >> 5;        // by 0..3
    gemm_core128(h2o, HH, (long)bx * 128, wo2b + (long)by * 128 * HH, HH, HH,
                 bo2 + by * 128, out_prev + by * 128, (long)TT * OUTF,
                 o1t_prev + by * 128, OUTF, 2);
  }
}

// D2: gi2 = h1 @ Wih2^T (bf16) | o1t = tanh(h1 @ Wo1^T + bo1) (f32). 896.
__global__ __launch_bounds__(256)
void k_gi2_o1(const unsigned short* __restrict__ h1n,
              const unsigned short* __restrict__ Wih2, const float* __restrict__ bih2,
              unsigned short* __restrict__ gi2,
              const unsigned short* __restrict__ Wo1, const float* __restrict__ bo1,
              float* __restrict__ o1t)
{
  const int wg = xcd_swz(blockIdx.x, gridDim.x);   // 896
  const bool g = (wg < 768);
  const int idx = g ? wg : wg - 768;
  const int bx = idx & 31;
  const int by = idx >> 5;
  const unsigned short* Ww = g ? (Wih2 + (long)by * 128 * HH) : (Wo1 + (long)by * 128 * HH);
  const float* bias        = g ? (bih2 + by * 128)            : (bo1 + by * 128);
  void* C                  = g ? (void*)(gi2 + by * 128)      : (void*)(o1t + by * 128);
  const long ldc           = g ? (long)G3 : (long)OUTF;
  gemm_core128(h1n, HH, (long)bx * 128, Ww, HH, HH, bias, C, ldc,
               nullptr, 0, g ? 3 : 1);
}

// final step's output head (128 blocks)
__global__ __launch_bounds__(256)
void k_o2f(const unsigned short* __restrict__ h2n,
           const unsigned short* __restrict__ Wo2, const float* __restrict__ bo2,
           const float* __restrict__ o1t, float* __restrict__ outp)
{
  const int wg = xcd_swz(blockIdx.x, gridDim.x);   // 128
  const int bx = wg & 31;
  const int by = wg >> 5;
  gemm_core128(h2n, HH, (long)bx * 128, Wo2 + (long)by * 128 * HH, HH, HH,
               bo2 + by * 128, outp + by * 128, (long)TT * OUTF,
               o1t + by * 128, OUTF, 2);
}

__global__ __launch_bounds__(256)
void aux_reduce(const float* __restrict__ p, int n, float* __restrict__ out, float scale) {
  float s = 0.f;
  for (int i = threadIdx.x; i < n; i += 256) s += p[i];
#pragma unroll
  for (int off = 32; off > 0; off >>= 1) s += __shfl_down(s, off);
  __shared__ float wsum[4];
  if ((threadIdx.x & 63) == 0) wsum[threadIdx.x >> 6] = s;
  __syncthreads();
  if (threadIdx.x == 0) out[0] = (wsum[0] + wsum[1] + wsum[2] + wsum[3]) * scale;
}

extern "C" void kernel_launch(void* const* d_in, const int* in_sizes, int n_in,
                              void* d_out, int out_size, void* d_ws, size_t ws_size,
                              hipStream_t stream) {
  const float* x    = (const float*)d_in[0];
  const float* Wih1 = (const float*)d_in[1];
  const float* Whh1 = (const float*)d_in[2];
  const float* bih1 = (const float*)d_in[3];
  const float* bhh1 = (const float*)d_in[4];
  const float* Wih2 = (const float*)d_in[5];
  const float* Whh2 = (const float*)d_in[6];
  const float* bih2 = (const float*)d_in[7];
  const float* bhh2 = (const float*)d_in[8];
  const float* Wo1  = (const float*)d_in[9];
  const float* bo1  = (const float*)d_in[10];
  const float* Wo2  = (const float*)d_in[11];
  const float* bo2  = (const float*)d_in[12];

  char* ws = (char*)d_ws;
  size_t off = 0;
  auto alloc = [&](size_t bytes) {
    char* p = ws + off;
    off = (off + bytes + 255) & ~(size_t)255;
    return p;
  };

  unsigned short* xb    = (unsigned short*)alloc((size_t)BB * TT * INF * 2);
  unsigned short* wih1b = (unsigned short*)alloc((size_t)G3 * INF * 2);
  unsigned short* whh1b = (unsigned short*)alloc((size_t)G3 * HH * 2);
  unsigned short* wih2b = (unsigned short*)alloc((size_t)G3 * HH * 2);
  unsigned short* whh2b = (unsigned short*)alloc((size_t)G3 * HH * 2);
  unsigned short* wo1b  = (unsigned short*)alloc((size_t)OUTF * HH * 2);
  unsigned short* wo2b  = (unsigned short*)alloc((size_t)OUTF * HH * 2);
  unsigned short* h1buf[2], * h2buf[2];
  h1buf[0] = (unsigned short*)alloc((size_t)BB * HH * 2);
  h1buf[1] = (unsigned short*)alloc((size_t)BB * HH * 2);
  h2buf[0] = (unsigned short*)alloc((size_t)BB * HH * 2);
  h2buf[1] = (unsigned short*)alloc((size_t)BB * HH * 2);
  unsigned short* gi1b = (unsigned short*)alloc((size_t)BB * G3 * 2);
  unsigned short* gi2b = (unsigned short*)alloc((size_t)BB * G3 * 2);
  float* o1t  = (float*)alloc((size_t)BB * OUTF * 4);
  float* auxp = (float*)alloc((size_t)TT * 512 * 4);

  float* aux = (float*)d_out + (size_t)BB * TT * OUTF;

  auto cvt = [&](const float* src, unsigned short* dst, size_t n) {
    int n4 = (int)(n / 4);
    cvt_f32_to_bf16_x4<<<dim3((n4 + 255) / 256), dim3(256), 0, stream>>>(src, dst, n4);
  };
  cvt(x,    xb,    (size_t)BB * TT * INF);
  cvt(Wih1, wih1b, (size_t)G3 * INF);
  cvt(Whh1, whh1b, (size_t)G3 * HH);
  cvt(Wih2, wih2b, (size_t)G3 * HH);
  cvt(Whh2, whh2b, (size_t)G3 * HH);
  cvt(Wo1,  wo1b,  (size_t)OUTF * HH);
  cvt(Wo2,  wo2b,  (size_t)OUTF * HH);

  hipMemsetAsync(h1buf[0], 0, (size_t)BB * HH * 2, stream);
  hipMemsetAsync(h2buf[0], 0, (size_t)BB * HH * 2, stream);

  const dim3 blk(256);

  for (int t = 0; t < TT; ++t) {
    unsigned short* h1o = h1buf[t & 1], * h1n = h1buf[(t + 1) & 1];
    unsigned short* h2o = h2buf[t & 1], * h2n = h2buf[(t + 1) & 1];
    // gi1(t) and (t>0) the previous step's output head
    k_pre<<<dim3(t ? 896 : 768), blk, 0, stream>>>(
        xb + (size_t)t * INF, wih1b, bih1, gi1b,
        h2o, wo2b, bo2, o1t,
        (float*)d_out + (size_t)(t > 0 ? t - 1 : 0) * OUTF);
    // layer 1: fused gh1 + gate1 -> h1(t)
    k_ghg<false><<<dim3(512), blk, 0, stream>>>(h1o, whh1b, bhh1, gi1b, h1n, nullptr);
    // gi2 and o1 from h1(t)
    k_gi2_o1<<<dim3(896), blk, 0, stream>>>(h1n, wih2b, bih2, gi2b, wo1b, bo1, o1t);
    // layer 2: fused gh2 + gate2 (+ aux partial) -> h2(t)
    k_ghg<true><<<dim3(512), blk, 0, stream>>>(h2o, whh2b, bhh2, gi2b, h2n,
                                               auxp + (size_t)t * 512);
  }
  k_o2f<<<dim3(128), blk, 0, stream>>>(h2buf[TT & 1], wo2b, bo2, o1t,
                                       (float*)d_out + (size_t)(TT - 1) * OUTF);
  aux_reduce<<<dim3(1), blk, 0, stream>>>(auxp, TT * 512, aux,
                                          1.f / ((float)BB * (float)HH));
}

// Round 11
// 2095.627 us; speedup vs baseline: 1.0307x; 1.0307x over previous
//
#include <hip/hip_runtime.h>
#include <cstdint>

#define BB   4096
#define TT   7
#define INF  512
#define HH   1024
#define OUTF 512
#define G3   3072   // 3*H

typedef short bf16x8 __attribute__((ext_vector_type(8)));
typedef float f32x4  __attribute__((ext_vector_type(4)));

static __device__ __forceinline__ unsigned short f2bf(float f) {
  unsigned u = __float_as_uint(f);
  unsigned r = ((u >> 16) & 1u) + 0x7FFFu;   // RNE
  return (unsigned short)((u + r) >> 16);
}
static __device__ __forceinline__ float bf2f(unsigned short s) {
  return __uint_as_float(((unsigned)s) << 16);
}

#define GLDS16(gp, lp)                                                        \
  __builtin_amdgcn_global_load_lds(                                           \
      (const __attribute__((address_space(1))) void*)(gp),                    \
      (__attribute__((address_space(3))) void*)(lp), 16, 0, 0)

__device__ __forceinline__ int xcd_swz(int bid, int nwg) {
  return (bid & 7) * (nwg >> 3) + (bid >> 3);   // bijective: nwg % 8 == 0
}

__global__ __launch_bounds__(256)
void cvt_f32_to_bf16_x4(const float* __restrict__ in, unsigned short* __restrict__ out, int n4) {
  int i = blockIdx.x * 256 + threadIdx.x;
  if (i >= n4) return;
  const float4 v = ((const float4*)in)[i];
  ushort4 o;
  o.x = f2bf(v.x); o.y = f2bf(v.y); o.z = f2bf(v.z); o.w = f2bf(v.w);
  ((ushort4*)out)[i] = o;
}

// ---------------------------------------------------------------------------
// r6-verified GEMM core: C = A @ W^T + bias. bf16 in, f32 acc. BK=64,
// double-buffered, chunk-XOR swizzle (0 conflicts). STAGE(next) before
// compute; plain __syncthreads schedule.
// mode: 0 f32; 1 f32 tanh; 2 f32 tanh+add; 3 bf16.
// NOTE: exactly ONE gemm_core call per kernel (single __shared__ instance).
// ---------------------------------------------------------------------------
template<int BM, int BN, int WM, int WN, int GN>
__device__ __forceinline__ void gemm_core(
    const unsigned short* __restrict__ A, long lda, long bm,
    const unsigned short* __restrict__ Wp, long ldw, int K,
    const float* __restrict__ biasp,
    void* __restrict__ Cp, long ldc,
    const float* __restrict__ addp, long ldadd, int mode)
{
  constexpr int ABUF = BM * 64;
  constexpr int WBUF = BN * 64;
  constexpr int AR = (BM * 8) / 256;
  constexpr int WR = (BN * 8) / 256;
  __shared__ __attribute__((aligned(16))) unsigned short sm[2 * (ABUF + WBUF)];
  unsigned short* As = sm;
  unsigned short* Ws = sm + 2 * ABUF;
  __attribute__((address_space(3))) unsigned short* lAs =
      (__attribute__((address_space(3))) unsigned short*)As;
  __attribute__((address_space(3))) unsigned short* lWs =
      (__attribute__((address_space(3))) unsigned short*)Ws;

  const int tid  = threadIdx.x;
  const int lane = tid & 63;
  const int wid  = tid >> 6;
  const int wr = (wid / GN) * (WM * 16);
  const int wc = (wid % GN) * (WN * 16);
  const int fr = lane & 15;
  const int q2 = lane >> 4;

  const unsigned short* gpa[AR];
  const unsigned short* gpw[WR];
  int lofa[AR], lofw[WR];
#pragma unroll
  for (int r = 0; r < AR; ++r) {
    const int id = r * 256 + tid;
    const int row = id >> 3, cc = id & 7;
    gpa[r] = A + (bm + row) * lda + (cc ^ (row & 7)) * 8;
    lofa[r] = id * 8;
  }
#pragma unroll
  for (int r = 0; r < WR; ++r) {
    const int id = r * 256 + tid;
    const int row = id >> 3, cc = id & 7;
    gpw[r] = Wp + (long)row * ldw + (cc ^ (row & 7)) * 8;
    lofw[r] = id * 8;
  }

#define STAGE(buf, kt) do {                                                   \
    _Pragma("unroll")                                                         \
    for (int r = 0; r < AR; ++r) GLDS16(gpa[r] + (kt), lAs + (buf) * ABUF + lofa[r]); \
    _Pragma("unroll")                                                         \
    for (int r = 0; r < WR; ++r) GLDS16(gpw[r] + (kt), lWs + (buf) * WBUF + lofw[r]); \
  } while (0)

  f32x4 acc[WM][WN] = {};
  STAGE(0, 0);
  __syncthreads();
  const int NK = K >> 6;
  for (int it = 0; it < NK; ++it) {
    const int cur = it & 1;
    if (it + 1 < NK) STAGE(cur ^ 1, (it + 1) << 6);
#pragma unroll
    for (int ks = 0; ks < 2; ++ks) {
      bf16x8 af[WM], wf[WN];
#pragma unroll
      for (int i = 0; i < WM; ++i) {
        const int row = wr + i * 16 + fr;
        const int ch  = (ks * 4 + q2) ^ (row & 7);
        af[i] = *(const bf16x8*)&As[cur * ABUF + row * 64 + ch * 8];
      }
#pragma unroll
      for (int i = 0; i < WN; ++i) {
        const int row = wc + i * 16 + fr;
        const int ch  = (ks * 4 + q2) ^ (row & 7);
        wf[i] = *(const bf16x8*)&Ws[cur * WBUF + row * 64 + ch * 8];
      }
#pragma unroll
      for (int mi = 0; mi < WM; ++mi)
#pragma unroll
        for (int ni = 0; ni < WN; ++ni)
          acc[mi][ni] = __builtin_amdgcn_mfma_f32_16x16x32_bf16(af[mi], wf[ni], acc[mi][ni], 0, 0, 0);
    }
    __syncthreads();
  }
#undef STAGE

  const int q = lane >> 4;
#pragma unroll
  for (int ni = 0; ni < WN; ++ni) {
    const int col = wc + ni * 16 + fr;
    const float bv = biasp[col];
#pragma unroll
    for (int mi = 0; mi < WM; ++mi) {
      const long row = bm + wr + mi * 16 + q * 4;
#pragma unroll
      for (int j = 0; j < 4; ++j) {
        const float v = acc[mi][ni][j] + bv;
        if (mode == 0)      ((float*)Cp)[(row + j) * ldc + col] = v;
        else if (mode == 1) ((float*)Cp)[(row + j) * ldc + col] = tanhf(v);
        else if (mode == 2) ((float*)Cp)[(row + j) * ldc + col] = tanhf(v) + addp[(row + j) * ldadd + col];
        else                ((unsigned short*)Cp)[(row + j) * ldc + col] = f2bf(v);
      }
    }
  }
}

// gi1 (bf16 out, bias included): 768 blocks, K=512, A row-stride T*INF.
__global__ __launch_bounds__(256)
void k_gi1(const unsigned short* __restrict__ A,
           const unsigned short* __restrict__ W, const float* __restrict__ bias,
           unsigned short* __restrict__ C)
{
  const int wg = xcd_swz(blockIdx.x, gridDim.x);   // 768
  const int bx = wg & 31, by = wg >> 5;
  gemm_core<128,128,4,4,2>(A, (long)TT * INF, (long)bx * 128, W + (long)by * 128 * INF,
                           INF, INF, bias + by * 128, C + by * 128, G3, nullptr, 0, 3);
}

// gi2 = h1 @ Wih2^T (bf16, bias incl.) | o1t = tanh(h1 @ Wo1^T + bo1) (f32). 896.
__global__ __launch_bounds__(256)
void k_gi2_o1(const unsigned short* __restrict__ h1n,
              const unsigned short* __restrict__ Wih2, const float* __restrict__ bih2,
              unsigned short* __restrict__ gi2,
              const unsigned short* __restrict__ Wo1, const float* __restrict__ bo1,
              float* __restrict__ o1t)
{
  const int wg = xcd_swz(blockIdx.x, gridDim.x);   // 896
  const bool g = (wg < 768);
  const int idx = g ? wg : wg - 768;
  const int bx = idx & 31;
  const int by = idx >> 5;                         // g: 0..23, else 0..3
  const unsigned short* Ww = g ? (Wih2 + (long)by * 128 * HH) : (Wo1 + (long)by * 128 * HH);
  const float* bias        = g ? (bih2 + by * 128)            : (bo1 + by * 128);
  void* C                  = g ? (void*)(gi2 + by * 128)      : (void*)(o1t + by * 128);
  const long ldc           = g ? (long)G3 : (long)OUTF;
  gemm_core<128,128,4,4,2>(h1n, HH, (long)bx * 128, Ww, HH, HH, bias, C, ldc,
                           nullptr, 0, g ? 3 : 1);
}

// out[b,t,:] = tanh(h2 @ Wo2^T + bo2) + o1t   (64x64 tiles, 512 blocks)
__global__ __launch_bounds__(256)
void k_o2_out(const unsigned short* __restrict__ h2n,
              const unsigned short* __restrict__ Wo2, const float* __restrict__ bo2,
              const float* __restrict__ o1t, float* __restrict__ outp)
{
  const int wg = xcd_swz(blockIdx.x, gridDim.x);   // 512
  const int bx = wg % 64;
  const int by = wg / 64;
  gemm_core<64,64,2,2,2>(h2n, HH, (long)bx * 64, Wo2 + (long)by * 64 * HH, HH, HH,
                         bo2 + by * 64, outp + by * 64, (long)TT * OUTF,
                         o1t + by * 64, OUTF, 2);
}

// ---------------------------------------------------------------------------
// FUSED gh-GEMM + GRU gate (r10-verified: passed, absmax 0.0246, ~35 us).
// Block: rows [bm,bm+128) x hidden cols [cn,cn+64); B-staging = 192 W-rows
// (3 gate sections x 64). Wave tile 64 x (3x32): lane holds (r,z,n) of the
// SAME hidden unit in acc[mi][k], acc[mi][2+k], acc[mi][4+k] -> gate fully
// in-lane; gh never touches memory (stays f32 in regs).
// h ping-pong: reads hold, writes hnew (other blocks still read hold).
// ---------------------------------------------------------------------------
template<bool AUX>
__global__ __launch_bounds__(256)
void k_ghg(const unsigned short* __restrict__ hold,
           const unsigned short* __restrict__ Whh,   // [3072][1024]
           const float* __restrict__ bhh,            // [3072]
           const unsigned short* __restrict__ gi,    // [4096][3072] bf16 (incl. bih)
           unsigned short* __restrict__ hnew,        // [4096][1024] bf16
           float* __restrict__ auxp)                 // per-block partial (AUX)
{
  __shared__ __attribute__((aligned(16))) unsigned short sm[(128 + 192) * 64]; // 40 KB
  unsigned short* As = sm;              // [128][64]
  unsigned short* Ws = sm + 128 * 64;   // [192][64]
  __attribute__((address_space(3))) unsigned short* lAs =
      (__attribute__((address_space(3))) unsigned short*)As;
  __attribute__((address_space(3))) unsigned short* lWs =
      (__attribute__((address_space(3))) unsigned short*)Ws;

  const int wg = xcd_swz(blockIdx.x, gridDim.x);    // 512 blocks
  const long bm = (long)(wg & 31) * 128;
  const int  cn = (wg >> 5) * 64;

  const int tid  = threadIdx.x;
  const int lane = tid & 63;
  const int wid  = tid >> 6;
  const int wr  = (wid >> 1) * 64;
  const int wcs = (wid & 1) * 32;
  const int fr = lane & 15;
  const int q2 = lane >> 4;

  const unsigned short* gpa[4];
  const unsigned short* gpw[6];
  int lofa[4], lofw[6];
#pragma unroll
  for (int r = 0; r < 4; ++r) {
    const int id = r * 256 + tid;
    const int row = id >> 3, cc = id & 7;
    gpa[r] = hold + (bm + row) * HH + (cc ^ (row & 7)) * 8;
    lofa[r] = id * 8;
  }
#pragma unroll
  for (int r = 0; r < 6; ++r) {
    const int id = r * 256 + tid;
    const int row = id >> 3, cc = id & 7;      // row in [0,192)
    const int s = row >> 6, rr = row & 63;
    gpw[r] = Whh + ((long)(s * 1024 + cn + rr)) * HH + (cc ^ (row & 7)) * 8;
    lofw[r] = id * 8;
  }

  f32x4 acc[4][6] = {};
  for (int kt = 0; kt < HH; kt += 64) {
    if (kt) __syncthreads();
#pragma unroll
    for (int r = 0; r < 4; ++r) GLDS16(gpa[r] + kt, lAs + lofa[r]);
#pragma unroll
    for (int r = 0; r < 6; ++r) GLDS16(gpw[r] + kt, lWs + lofw[r]);
    __syncthreads();

#pragma unroll
    for (int ks = 0; ks < 2; ++ks) {
      bf16x8 af[4], wf[6];
#pragma unroll
      for (int i = 0; i < 4; ++i) {
        const int row = wr + i * 16 + fr;
        const int ch  = (ks * 4 + q2) ^ (row & 7);
        af[i] = *(const bf16x8*)&As[row * 64 + ch * 8];
      }
#pragma unroll
      for (int p = 0; p < 3; ++p)
#pragma unroll
        for (int k2 = 0; k2 < 2; ++k2) {
          const int row = p * 64 + wcs + k2 * 16 + fr;
          const int ch  = (ks * 4 + q2) ^ (row & 7);
          wf[p * 2 + k2] = *(const bf16x8*)&Ws[row * 64 + ch * 8];
        }
#pragma unroll
      for (int mi = 0; mi < 4; ++mi)
#pragma unroll
        for (int ni = 0; ni < 6; ++ni)
          acc[mi][ni] = __builtin_amdgcn_mfma_f32_16x16x32_bf16(af[mi], wf[ni], acc[mi][ni], 0, 0, 0);
    }
  }

  // fused gate epilogue: h = (1-z)*n + z*h_old, all in-lane
  const int q = lane >> 4;
  float vsum = 0.f;
#pragma unroll
  for (int k2 = 0; k2 < 2; ++k2) {
    const int c = cn + wcs + k2 * 16 + fr;
    const float br = bhh[c], bz = bhh[1024 + c], bn = bhh[2048 + c];
#pragma unroll
    for (int mi = 0; mi < 4; ++mi) {
      const long row = bm + wr + mi * 16 + q * 4;
#pragma unroll
      for (int j = 0; j < 4; ++j) {
        const long rj = row + j;
        const float ghr = acc[mi][k2][j]     + br;
        const float ghz = acc[mi][2 + k2][j] + bz;
        const float ghn = acc[mi][4 + k2][j] + bn;
        const unsigned short* gp = gi + rj * G3 + c;
        const float gir = bf2f(gp[0]);
        const float giz = bf2f(gp[HH]);
        const float gin = bf2f(gp[2 * HH]);
        const float r = 1.f / (1.f + __expf(-(gir + ghr)));
        const float z = 1.f / (1.f + __expf(-(giz + ghz)));
        const float n = tanhf(gin + r * ghn);
        const float ho = bf2f(hold[rj * HH + c]);
        const float h = (1.f - z) * n + z * ho;
        hnew[rj * HH + c] = f2bf(h);
        if (AUX) vsum += h * h;
      }
    }
  }
  if (AUX) {
#pragma unroll
    for (int off = 32; off > 0; off >>= 1) vsum += __shfl_down(vsum, off);
    __shared__ float wsum[4];
    if (lane == 0) wsum[wid] = vsum;
    __syncthreads();
    if (tid == 0) auxp[blockIdx.x] = wsum[0] + wsum[1] + wsum[2] + wsum[3];
  }
}

__global__ __launch_bounds__(256)
void aux_reduce(const float* __restrict__ p, int n, float* __restrict__ out, float scale) {
  float s = 0.f;
  for (int i = threadIdx.x; i < n; i += 256) s += p[i];
#pragma unroll
  for (int off = 32; off > 0; off >>= 1) s += __shfl_down(s, off);
  __shared__ float wsum[4];
  if ((threadIdx.x & 63) == 0) wsum[threadIdx.x >> 6] = s;
  __syncthreads();
  if (threadIdx.x == 0) out[0] = (wsum[0] + wsum[1] + wsum[2] + wsum[3]) * scale;
}

extern "C" void kernel_launch(void* const* d_in, const int* in_sizes, int n_in,
                              void* d_out, int out_size, void* d_ws, size_t ws_size,
                              hipStream_t stream) {
  const float* x    = (const float*)d_in[0];
  const float* Wih1 = (const float*)d_in[1];
  const float* Whh1 = (const float*)d_in[2];
  const float* bih1 = (const float*)d_in[3];
  const float* bhh1 = (const float*)d_in[4];
  const float* Wih2 = (const float*)d_in[5];
  const float* Whh2 = (const float*)d_in[6];
  const float* bih2 = (const float*)d_in[7];
  const float* bhh2 = (const float*)d_in[8];
  const float* Wo1  = (const float*)d_in[9];
  const float* bo1  = (const float*)d_in[10];
  const float* Wo2  = (const float*)d_in[11];
  const float* bo2  = (const float*)d_in[12];

  char* ws = (char*)d_ws;
  size_t off = 0;
  auto alloc = [&](size_t bytes) {
    char* p = ws + off;
    off = (off + bytes + 255) & ~(size_t)255;
    return p;
  };

  unsigned short* xb    = (unsigned short*)alloc((size_t)BB * TT * INF * 2);
  unsigned short* wih1b = (unsigned short*)alloc((size_t)G3 * INF * 2);
  unsigned short* whh1b = (unsigned short*)alloc((size_t)G3 * HH * 2);
  unsigned short* wih2b = (unsigned short*)alloc((size_t)G3 * HH * 2);
  unsigned short* whh2b = (unsigned short*)alloc((size_t)G3 * HH * 2);
  unsigned short* wo1b  = (unsigned short*)alloc((size_t)OUTF * HH * 2);
  unsigned short* wo2b  = (unsigned short*)alloc((size_t)OUTF * HH * 2);
  unsigned short* h1buf[2], * h2buf[2];
  h1buf[0] = (unsigned short*)alloc((size_t)BB * HH * 2);
  h1buf[1] = (unsigned short*)alloc((size_t)BB * HH * 2);
  h2buf[0] = (unsigned short*)alloc((size_t)BB * HH * 2);
  h2buf[1] = (unsigned short*)alloc((size_t)BB * HH * 2);
  unsigned short* gi1b = (unsigned short*)alloc((size_t)BB * G3 * 2);
  unsigned short* gi2b = (unsigned short*)alloc((size_t)BB * G3 * 2);
  float* o1t  = (float*)alloc((size_t)BB * OUTF * 4);
  float* auxp = (float*)alloc((size_t)TT * 512 * 4);

  float* aux = (float*)d_out + (size_t)BB * TT * OUTF;

  auto cvt = [&](const float* src, unsigned short* dst, size_t n) {
    int n4 = (int)(n / 4);
    cvt_f32_to_bf16_x4<<<dim3((n4 + 255) / 256), dim3(256), 0, stream>>>(src, dst, n4);
  };
  cvt(x,    xb,    (size_t)BB * TT * INF);
  cvt(Wih1, wih1b, (size_t)G3 * INF);
  cvt(Whh1, whh1b, (size_t)G3 * HH);
  cvt(Wih2, wih2b, (size_t)G3 * HH);
  cvt(Whh2, whh2b, (size_t)G3 * HH);
  cvt(Wo1,  wo1b,  (size_t)OUTF * HH);
  cvt(Wo2,  wo2b,  (size_t)OUTF * HH);

  hipMemsetAsync(h1buf[0], 0, (size_t)BB * HH * 2, stream);
  hipMemsetAsync(h2buf[0], 0, (size_t)BB * HH * 2, stream);

  const dim3 blk(256);

  for (int t = 0; t < TT; ++t) {
    unsigned short* h1o = h1buf[t & 1], * h1n = h1buf[(t + 1) & 1];
    unsigned short* h2o = h2buf[t & 1], * h2n = h2buf[(t + 1) & 1];
    k_gi1<<<dim3(768), blk, 0, stream>>>(xb + (size_t)t * INF, wih1b, bih1, gi1b);
    k_ghg<false><<<dim3(512), blk, 0, stream>>>(h1o, whh1b, bhh1, gi1b, h1n, nullptr);
    k_gi2_o1<<<dim3(896), blk, 0, stream>>>(h1n, wih2b, bih2, gi2b, wo1b, bo1, o1t);
    k_ghg<true><<<dim3(512), blk, 0, stream>>>(h2o, whh2b, bhh2, gi2b, h2n,
                                               auxp + (size_t)t * 512);
    k_o2_out<<<dim3(512), blk, 0, stream>>>(h2n, wo2b, bo2, o1t,
                                            (float*)d_out + (size_t)t * OUTF);
  }
  aux_reduce<<<dim3(1), blk, 0, stream>>>(auxp, TT * 512, aux,
                                          1.f / ((float)BB * (float)HH));
}

// Round 12
// 1390.989 us; speedup vs baseline: 1.5528x; 1.5066x over previous
//
#include <hip/hip_runtime.h>
#include <cstdint>

#define BB   4096
#define TT   7
#define INF  512
#define HH   1024
#define OUTF 512
#define G3   3072   // 3*H

typedef short bf16x8 __attribute__((ext_vector_type(8)));
typedef float f32x4  __attribute__((ext_vector_type(4)));

static __device__ __forceinline__ unsigned short f2bf(float f) {
  unsigned u = __float_as_uint(f);
  unsigned r = ((u >> 16) & 1u) + 0x7FFFu;   // RNE
  return (unsigned short)((u + r) >> 16);
}
static __device__ __forceinline__ float bf2f(unsigned short s) {
  return __uint_as_float(((unsigned)s) << 16);
}

#define GLDS16(gp, lp)                                                        \
  __builtin_amdgcn_global_load_lds(                                           \
      (const __attribute__((address_space(1))) void*)(gp),                    \
      (__attribute__((address_space(3))) void*)(lp), 16, 0, 0)

__device__ __forceinline__ int xcd_swz(int bid, int nwg) {
  return (bid & 7) * (nwg >> 3) + (bid >> 3);   // bijective: nwg % 8 == 0
}

__global__ __launch_bounds__(256)
void cvt_f32_to_bf16_x4(const float* __restrict__ in, unsigned short* __restrict__ out, int n4) {
  int i = blockIdx.x * 256 + threadIdx.x;
  if (i >= n4) return;
  const float4 v = ((const float4*)in)[i];
  ushort4 o;
  o.x = f2bf(v.x); o.y = f2bf(v.y); o.z = f2bf(v.z); o.w = f2bf(v.w);
  ((ushort4*)out)[i] = o;
}

// x [B][T][INF] f32  ->  xbT [T][B][INF] bf16 (both sides coalesced in INF)
__global__ __launch_bounds__(256)
void cvt_x_transpose(const float* __restrict__ in, unsigned short* __restrict__ out) {
  const int i4 = blockIdx.x * 256 + threadIdx.x;   // over B*T*INF/4
  const long e = (long)i4 << 2;
  const int i  = (int)(e & (INF - 1));
  const long bt = e >> 9;                          // b*T + t
  const int t = (int)(bt % TT), b = (int)(bt / TT);
  const float4 v = *(const float4*)(in + e);
  ushort4 o;
  o.x = f2bf(v.x); o.y = f2bf(v.y); o.z = f2bf(v.z); o.w = f2bf(v.w);
  *(ushort4*)(out + ((size_t)t * BB + b) * INF + i) = o;
}

// ---------------------------------------------------------------------------
// r6-verified GEMM core (best measured config): C = A @ W^T + bias.
// bf16 in, f32 acc. BK=64, double-buffered, chunk-XOR swizzle (0 conflicts).
// STAGE(next) before compute; plain __syncthreads schedule.
// mode: 0 f32; 1 f32 tanh; 2 f32 tanh+add; 3 bf16.
// NOTE: exactly ONE gemm_core call per kernel (single __shared__ instance).
// ---------------------------------------------------------------------------
template<int BM, int BN, int WM, int WN, int GN>
__device__ __forceinline__ void gemm_core(
    const unsigned short* __restrict__ A, long lda, long bm,
    const unsigned short* __restrict__ Wp, long ldw, int K,
    const float* __restrict__ biasp,
    void* __restrict__ Cp, long ldc,
    const float* __restrict__ addp, long ldadd, int mode)
{
  constexpr int ABUF = BM * 64;
  constexpr int WBUF = BN * 64;
  constexpr int AR = (BM * 8) / 256;
  constexpr int WR = (BN * 8) / 256;
  __shared__ __attribute__((aligned(16))) unsigned short sm[2 * (ABUF + WBUF)];
  unsigned short* As = sm;
  unsigned short* Ws = sm + 2 * ABUF;
  __attribute__((address_space(3))) unsigned short* lAs =
      (__attribute__((address_space(3))) unsigned short*)As;
  __attribute__((address_space(3))) unsigned short* lWs =
      (__attribute__((address_space(3))) unsigned short*)Ws;

  const int tid  = threadIdx.x;
  const int lane = tid & 63;
  const int wid  = tid >> 6;
  const int wr = (wid / GN) * (WM * 16);
  const int wc = (wid % GN) * (WN * 16);
  const int fr = lane & 15;
  const int q2 = lane >> 4;

  const unsigned short* gpa[AR];
  const unsigned short* gpw[WR];
  int lofa[AR], lofw[WR];
#pragma unroll
  for (int r = 0; r < AR; ++r) {
    const int id = r * 256 + tid;
    const int row = id >> 3, cc = id & 7;
    gpa[r] = A + (bm + row) * lda + (cc ^ (row & 7)) * 8;
    lofa[r] = id * 8;
  }
#pragma unroll
  for (int r = 0; r < WR; ++r) {
    const int id = r * 256 + tid;
    const int row = id >> 3, cc = id & 7;
    gpw[r] = Wp + (long)row * ldw + (cc ^ (row & 7)) * 8;
    lofw[r] = id * 8;
  }

#define STAGE(buf, kt) do {                                                   \
    _Pragma("unroll")                                                         \
    for (int r = 0; r < AR; ++r) GLDS16(gpa[r] + (kt), lAs + (buf) * ABUF + lofa[r]); \
    _Pragma("unroll")                                                         \
    for (int r = 0; r < WR; ++r) GLDS16(gpw[r] + (kt), lWs + (buf) * WBUF + lofw[r]); \
  } while (0)

  f32x4 acc[WM][WN] = {};
  STAGE(0, 0);
  __syncthreads();
  const int NK = K >> 6;
  for (int it = 0; it < NK; ++it) {
    const int cur = it & 1;
    if (it + 1 < NK) STAGE(cur ^ 1, (it + 1) << 6);
#pragma unroll
    for (int ks = 0; ks < 2; ++ks) {
      bf16x8 af[WM], wf[WN];
#pragma unroll
      for (int i = 0; i < WM; ++i) {
        const int row = wr + i * 16 + fr;
        const int ch  = (ks * 4 + q2) ^ (row & 7);
        af[i] = *(const bf16x8*)&As[cur * ABUF + row * 64 + ch * 8];
      }
#pragma unroll
      for (int i = 0; i < WN; ++i) {
        const int row = wc + i * 16 + fr;
        const int ch  = (ks * 4 + q2) ^ (row & 7);
        wf[i] = *(const bf16x8*)&Ws[cur * WBUF + row * 64 + ch * 8];
      }
#pragma unroll
      for (int mi = 0; mi < WM; ++mi)
#pragma unroll
        for (int ni = 0; ni < WN; ++ni)
          acc[mi][ni] = __builtin_amdgcn_mfma_f32_16x16x32_bf16(af[mi], wf[ni], acc[mi][ni], 0, 0, 0);
    }
    __syncthreads();
  }
#undef STAGE

  const int q = lane >> 4;
#pragma unroll
  for (int ni = 0; ni < WN; ++ni) {
    const int col = wc + ni * 16 + fr;
    const float bv = biasp[col];
#pragma unroll
    for (int mi = 0; mi < WM; ++mi) {
      const long row = bm + wr + mi * 16 + q * 4;
#pragma unroll
      for (int j = 0; j < 4; ++j) {
        const float v = acc[mi][ni][j] + bv;
        if (mode == 0)      ((float*)Cp)[(row + j) * ldc + col] = v;
        else if (mode == 1) ((float*)Cp)[(row + j) * ldc + col] = tanhf(v);
        else if (mode == 2) ((float*)Cp)[(row + j) * ldc + col] = tanhf(v) + addp[(row + j) * ldadd + col];
        else                ((unsigned short*)Cp)[(row + j) * ldc + col] = f2bf(v);
      }
    }
  }
}

// gi1 (bf16 out, bias incl.). Hoisted: A = xbT (M = Th*4096, lda = INF),
// gx = Th*32, C rows map to slabs [t][b]. Per-step: A = xbT + t*BB*INF, gx=32.
__global__ __launch_bounds__(256)
void k_gi1(const unsigned short* __restrict__ A,
           const unsigned short* __restrict__ W, const float* __restrict__ bias,
           unsigned short* __restrict__ C, int gx)
{
  const int wg = xcd_swz(blockIdx.x, gridDim.x);
  const int bx = wg % gx, by = wg / gx;
  gemm_core<128,128,4,4,2>(A, INF, (long)bx * 128, W + (long)by * 128 * INF,
                           INF, INF, bias + by * 128, C + by * 128, G3, nullptr, 0, 3);
}

// gh1 = h1 @ Whh1^T and gh2 = h2 @ Whh2^T in one 1536-block dispatch (bf16 out)
__global__ __launch_bounds__(256)
void k_gh_dual(const unsigned short* __restrict__ h1b, const unsigned short* __restrict__ h2b,
               const unsigned short* __restrict__ W1, const unsigned short* __restrict__ W2,
               const float* __restrict__ b1, const float* __restrict__ b2,
               unsigned short* __restrict__ gh1, unsigned short* __restrict__ gh2)
{
  const int wg = xcd_swz(blockIdx.x, gridDim.x);   // 1536
  const int bx = wg % 32;
  const int by = (wg / 32) % 24;
  const int z  = wg / (32 * 24);
  const unsigned short* Aa = z ? h2b : h1b;
  const unsigned short* Ww = (z ? W2 : W1) + (long)by * 128 * HH;
  const float* bias = (z ? b2 : b1) + by * 128;
  unsigned short* C = (z ? gh2 : gh1) + by * 128;
  gemm_core<128,128,4,4,2>(Aa, HH, (long)bx * 128, Ww, HH, HH, bias, C, G3, nullptr, 0, 3);
}

// gi2 = h1 @ Wih2^T (bf16) and o1t = tanh(h1 @ Wo1^T + bo1) (f32), one call site
__global__ __launch_bounds__(256)
void k_gi2_o1(const unsigned short* __restrict__ h1b,
              const unsigned short* __restrict__ Wih2, const float* __restrict__ bih2,
              unsigned short* __restrict__ gi2,
              const unsigned short* __restrict__ Wo1, const float* __restrict__ bo1,
              float* __restrict__ o1t)
{
  const int wg = xcd_swz(blockIdx.x, gridDim.x);   // 896
  const int bx = wg % 32;
  const int by = wg / 32;
  const bool g = (by < 24);
  const int bo = by - 24;
  const unsigned short* Ww = g ? (Wih2 + (long)by * 128 * HH) : (Wo1 + (long)bo * 128 * HH);
  const float* bias        = g ? (bih2 + by * 128)            : (bo1 + bo * 128);
  void* C                  = g ? (void*)(gi2 + by * 128)      : (void*)(o1t + bo * 128);
  const long ldc           = g ? (long)G3 : (long)OUTF;
  gemm_core<128,128,4,4,2>(h1b, HH, (long)bx * 128, Ww, HH, HH, bias, C, ldc,
                           nullptr, 0, g ? 3 : 1);
}

// out[b,t,:] = tanh(h2 @ Wo2^T + bo2) + o1t   (64x64 tiles, 512 blocks)
__global__ __launch_bounds__(256)
void k_o2_out(const unsigned short* __restrict__ h2b,
              const unsigned short* __restrict__ Wo2, const float* __restrict__ bo2,
              const float* __restrict__ o1t, float* __restrict__ outp)
{
  const int wg = xcd_swz(blockIdx.x, gridDim.x);   // 512
  const int bx = wg % 64;
  const int by = wg / 64;
  gemm_core<64,64,2,2,2>(h2b, HH, (long)bx * 64, Wo2 + (long)by * 64 * HH, HH, HH,
                         bo2 + by * 64, outp + by * 64, (long)TT * OUTF,
                         o1t + by * 64, OUTF, 2);
}

// GRU gate: h = (1-z)*n + z*h_old. gi, gh bf16; recurrence on bf16 hb (in-place).
__global__ __launch_bounds__(256)
void k_gate(const unsigned short* __restrict__ gi, long gistride,
            const unsigned short* __restrict__ gh,
            unsigned short* __restrict__ hb,
            float* __restrict__ auxp)
{
  const int i4 = blockIdx.x * 256 + threadIdx.x;
  const int e  = i4 << 2;
  const int b = e >> 10;                  // H = 1024
  const int c = e & 1023;
  const unsigned short* g = gi + (long)b * gistride + c;
  const ushort4 a0 = *(const ushort4*)(g);
  const ushort4 a1 = *(const ushort4*)(g + HH);
  const ushort4 a2 = *(const ushort4*)(g + 2 * HH);
  const unsigned short* gg = gh + (long)b * G3 + c;
  const ushort4 b0 = *(const ushort4*)(gg);
  const ushort4 b1 = *(const ushort4*)(gg + HH);
  const ushort4 b2 = *(const ushort4*)(gg + 2 * HH);
  const f32x4 ir  = f32x4{bf2f(a0.x), bf2f(a0.y), bf2f(a0.z), bf2f(a0.w)};
  const f32x4 iz  = f32x4{bf2f(a1.x), bf2f(a1.y), bf2f(a1.z), bf2f(a1.w)};
  const f32x4 inn = f32x4{bf2f(a2.x), bf2f(a2.y), bf2f(a2.z), bf2f(a2.w)};
  const f32x4 hr  = f32x4{bf2f(b0.x), bf2f(b0.y), bf2f(b0.z), bf2f(b0.w)};
  const f32x4 hz  = f32x4{bf2f(b1.x), bf2f(b1.y), bf2f(b1.z), bf2f(b1.w)};
  const f32x4 hn  = f32x4{bf2f(b2.x), bf2f(b2.y), bf2f(b2.z), bf2f(b2.w)};
  const ushort4 ho = *(const ushort4*)(hb + e);
  const f32x4 h = f32x4{bf2f(ho.x), bf2f(ho.y), bf2f(ho.z), bf2f(ho.w)};
  f32x4 hnew;
  float vsum = 0.f;
#pragma unroll
  for (int j = 0; j < 4; ++j) {
    const float r = 1.f / (1.f + __expf(-(ir[j] + hr[j])));
    const float z = 1.f / (1.f + __expf(-(iz[j] + hz[j])));
    const float n = tanhf(inn[j] + r * hn[j]);
    hnew[j] = (1.f - z) * n + z * h[j];
    vsum += hnew[j] * hnew[j];
  }
  ushort4 o;
  o.x = f2bf(hnew[0]); o.y = f2bf(hnew[1]); o.z = f2bf(hnew[2]); o.w = f2bf(hnew[3]);
  *(ushort4*)(hb + e) = o;
  if (auxp != nullptr) {
#pragma unroll
    for (int off = 32; off > 0; off >>= 1) vsum += __shfl_down(vsum, off);
    __shared__ float wsum[4];
    if ((threadIdx.x & 63) == 0) wsum[threadIdx.x >> 6] = vsum;
    __syncthreads();
    if (threadIdx.x == 0) auxp[blockIdx.x] = wsum[0] + wsum[1] + wsum[2] + wsum[3];
  }
}

__global__ __launch_bounds__(256)
void aux_reduce(const float* __restrict__ p, int n, float* __restrict__ out, float scale) {
  float s = 0.f;
  for (int i = threadIdx.x; i < n; i += 256) s += p[i];
#pragma unroll
  for (int off = 32; off > 0; off >>= 1) s += __shfl_down(s, off);
  __shared__ float wsum[4];
  if ((threadIdx.x & 63) == 0) wsum[threadIdx.x >> 6] = s;
  __syncthreads();
  if (threadIdx.x == 0) out[0] = (wsum[0] + wsum[1] + wsum[2] + wsum[3]) * scale;
}

extern "C" void kernel_launch(void* const* d_in, const int* in_sizes, int n_in,
                              void* d_out, int out_size, void* d_ws, size_t ws_size,
                              hipStream_t stream) {
  const float* x    = (const float*)d_in[0];
  const float* Wih1 = (const float*)d_in[1];
  const float* Whh1 = (const float*)d_in[2];
  const float* bih1 = (const float*)d_in[3];
  const float* bhh1 = (const float*)d_in[4];
  const float* Wih2 = (const float*)d_in[5];
  const float* Whh2 = (const float*)d_in[6];
  const float* bih2 = (const float*)d_in[7];
  const float* bhh2 = (const float*)d_in[8];
  const float* Wo1  = (const float*)d_in[9];
  const float* bo1  = (const float*)d_in[10];
  const float* Wo2  = (const float*)d_in[11];
  const float* bo2  = (const float*)d_in[12];

  char* ws = (char*)d_ws;
  size_t off = 0;
  auto alloc = [&](size_t bytes) {
    char* p = ws + off;
    off = (off + bytes + 255) & ~(size_t)255;
    return p;
  };

  unsigned short* xbT   = (unsigned short*)alloc((size_t)BB * TT * INF * 2);  // [T][B][INF]
  unsigned short* wih1b = (unsigned short*)alloc((size_t)G3 * INF * 2);
  unsigned short* whh1b = (unsigned short*)alloc((size_t)G3 * HH * 2);
  unsigned short* wih2b = (unsigned short*)alloc((size_t)G3 * HH * 2);
  unsigned short* whh2b = (unsigned short*)alloc((size_t)G3 * HH * 2);
  unsigned short* wo1b  = (unsigned short*)alloc((size_t)OUTF * HH * 2);
  unsigned short* wo2b  = (unsigned short*)alloc((size_t)OUTF * HH * 2);
  unsigned short* h1b = (unsigned short*)alloc((size_t)BB * HH * 2);
  unsigned short* h2b = (unsigned short*)alloc((size_t)BB * HH * 2);
  unsigned short* gh1 = (unsigned short*)alloc((size_t)BB * G3 * 2);  // also gi2
  unsigned short* gh2 = (unsigned short*)alloc((size_t)BB * G3 * 2);
  float* o1t  = (float*)alloc((size_t)BB * OUTF * 4);
  float* auxp = (float*)alloc((size_t)TT * (BB * HH / 1024) * 4);
  unsigned short* gi2 = gh1;          // gh1 dead after gate1; stream order safe

  // gi1 slabs: hoist as many steps as the workspace allows (>=1 always fits:
  // base ~129 MB, r2-era evidence ws >= ~205 MB).
  const size_t slab = (size_t)BB * G3 * 2;
  int Th = (int)((ws_size > off ? (ws_size - off) : 0) / (slab + 256));
  if (Th < 1) Th = 1;
  if (Th > TT) Th = TT;
  unsigned short* gi1s = (unsigned short*)alloc((size_t)Th * slab);

  float* aux = (float*)d_out + (size_t)BB * TT * OUTF;

  auto cvt = [&](const float* src, unsigned short* dst, size_t n) {
    int n4 = (int)(n / 4);
    cvt_f32_to_bf16_x4<<<dim3((n4 + 255) / 256), dim3(256), 0, stream>>>(src, dst, n4);
  };
  cvt_x_transpose<<<dim3(BB * TT * INF / 1024), dim3(256), 0, stream>>>(x, xbT);
  cvt(Wih1, wih1b, (size_t)G3 * INF);
  cvt(Whh1, whh1b, (size_t)G3 * HH);
  cvt(Wih2, wih2b, (size_t)G3 * HH);
  cvt(Whh2, whh2b, (size_t)G3 * HH);
  cvt(Wo1,  wo1b,  (size_t)OUTF * HH);
  cvt(Wo2,  wo2b,  (size_t)OUTF * HH);

  hipMemsetAsync(h1b, 0, (size_t)BB * HH * 2, stream);
  hipMemsetAsync(h2b, 0, (size_t)BB * HH * 2, stream);

  const dim3 blk(256);
  const int gateGrid = BB * HH / 1024;   // 4096

  // hoisted gi1 for steps [0, Th): one big GEMM, M = Th*4096
  k_gi1<<<dim3(Th * 768), blk, 0, stream>>>(xbT, wih1b, bih1, gi1s, Th * 32);

  for (int t = 0; t < TT; ++t) {
    const unsigned short* gi1_t;
    if (t < Th) {
      gi1_t = gi1s + (size_t)t * slab / 2;        // slab in ushorts
    } else {
      // recompute into slab 0 (its hoisted content was consumed at t=0)
      k_gi1<<<dim3(768), blk, 0, stream>>>(xbT + (size_t)t * BB * INF,
                                           wih1b, bih1, gi1s, 32);
      gi1_t = gi1s;
    }
    k_gh_dual<<<dim3(1536), blk, 0, stream>>>(h1b, h2b, whh1b, whh2b, bhh1, bhh2, gh1, gh2);
    k_gate<<<dim3(gateGrid), blk, 0, stream>>>(gi1_t, (long)G3, gh1, h1b, nullptr);
    k_gi2_o1<<<dim3(896), blk, 0, stream>>>(h1b, wih2b, bih2, gi2, wo1b, bo1, o1t);
    k_gate<<<dim3(gateGrid), blk, 0, stream>>>(gi2, (long)G3, gh2, h2b,
                                               auxp + (size_t)t * gateGrid);
    k_o2_out<<<dim3(512), blk, 0, stream>>>(h2b, wo2b, bo2, o1t,
                                            (float*)d_out + (size_t)t * OUTF);
  }
  aux_reduce<<<dim3(1), blk, 0, stream>>>(auxp, TT * gateGrid, aux,
                                          1.f / ((float)BB * (float)HH));
}